// Round 3
// baseline (1385.254 us; speedup 1.0000x reference)
//
#include <hip/hip_runtime.h>
#include <hip/hip_bf16.h>

typedef __attribute__((ext_vector_type(8))) short short8;   // 8 bf16 (4 VGPR) MFMA A/B frag
typedef __attribute__((ext_vector_type(4))) short short4v;  // 4 bf16 (8B)
typedef __attribute__((ext_vector_type(4))) float f32x4;    // MFMA C/D frag

#define D_IN 1280
#define D_OUT 1280
#define RANK 4
#define LORA_STRIDE 4
#define BK 64
#define BN 128

// fp32 -> bf16 round-to-nearest-even, bit-cast to short for LDS storage
__device__ __forceinline__ short f2bs(float f) {
    __hip_bfloat16 h = __float2bfloat16(f);
    return __builtin_bit_cast(short, h);
}

// LDS layout: row-major [row][64 bf16], 16-B chunk index XORed with (row&7)
// to spread banks for both staging writes and b128 frag reads. (0 measured
// bank conflicts — do not touch.)
__device__ __forceinline__ int swz(int row, int k) {
    return row * BK + ((((k >> 3) ^ row) & 7) << 3) + (k & 7);
}

// ---------------------------------------------------------------------------
// Main kernel: BM=256, BN=128, 512 threads (8 waves, 4m x 2n of 64x64).
// W_eff staging (the expensive per-K-step chain) feeds 2x the output of the
// BM=128 version -> per-output staging cost halves; u[8]->u[4] frees 16 VGPR
// so __launch_bounds__(512,4) reaches 4 waves/SIMD (2x occupancy of round-0).
// ---------------------------------------------------------------------------
__global__ __launch_bounds__(512, 4)
void lora_fused_gemm_bm256(const float* __restrict__ x,      // [M][D_IN]
                           const int* __restrict__ lora_id,  // [G]
                           const float* __restrict__ W,      // [D_OUT][D_IN]
                           const float* __restrict__ Wd,     // [L][RANK][D_IN]
                           const float* __restrict__ Wu,     // [L][D_OUT][RANK]
                           float* __restrict__ out,          // [M][D_OUT]
                           int t_len, int ntiles_n) {
    const int BM = 256;
    __shared__ short sA[256 * BK];  // 32 KB
    __shared__ short sB[BN * BK];   // 16 KB

    const int tid = threadIdx.x;

    // T1: XCD-aware chunked remap (proven: halves FETCH by keeping an
    // m-tile's n-blocks on one XCD's L2). nwg = 2560, divisible by 8.
    const int nwg = gridDim.x;
    const int cpx = nwg >> 3;
    const int bsw = (blockIdx.x & 7) * cpx + (blockIdx.x >> 3);
    const int ntile = bsw % ntiles_n;   // n fast within the chunk
    const int mtile = bsw / ntiles_n;
    const int gm = mtile * BM;
    const int gn = ntile * BN;

    const int chunk = gm / t_len;       // block-uniform (BM divides t_len)
    const int lid_raw = lora_id[chunk];
    const bool active = lid_raw >= 0;
    const int idx = active ? (lid_raw / LORA_STRIDE) : 0;
    const float lscale = active ? 1.0f : 0.0f;  // SCALE = 1.0

    // ---- A staging: 256 rows x 64 k by 512 threads ----
    // row = tid>>1 (0..255), 32 contiguous k at (tid&1)*32
    const int arow = tid >> 1;
    const int acol = (tid & 1) * 32;
    const float* xp = x + (long)(gm + arow) * D_IN + acol;

    // ---- B staging: 128 rows x 64 k by 512 threads ----
    // k-group kg of 4 (16 groups), rows nr + 32*s, s=0..3
    const int kg = tid & 15;
    const int nr = tid >> 4;            // 0..31
    const float* wp = W + (long)gn * D_IN + kg * 4;
    const float* wdp = Wd + (long)idx * RANK * D_IN + kg * 4;

    // Wu columns for this thread's 4 n-rows: fixed over the K-loop; pre-scaled
    f32x4 u[4];
    #pragma unroll
    for (int s = 0; s < 4; ++s) {
        f32x4 t = *reinterpret_cast<const f32x4*>(
            Wu + ((long)idx * D_OUT + gn + nr + 32 * s) * RANK);
        #pragma unroll
        for (int j = 0; j < 4; ++j) u[s][j] = t[j] * lscale;
    }

    // ---- MFMA wave layout: 4m x 2n waves, each 64x64 = 4x4 tiles of 16x16 ----
    const int wave = tid >> 6;
    const int lane = tid & 63;
    const int wm = (wave & 3) * 64;
    const int wn = (wave >> 2) * 64;
    const int quad = lane >> 4;
    const int lr = lane & 15;

    f32x4 acc[4][4];
    #pragma unroll
    for (int a = 0; a < 4; ++a)
        #pragma unroll
        for (int b = 0; b < 4; ++b)
            #pragma unroll
            for (int j = 0; j < 4; ++j) acc[a][b][j] = 0.f;

    for (int k0 = 0; k0 < D_IN; k0 += BK) {
        if (k0) __syncthreads();  // protect LDS while previous MFMAs read

        // ---- stage A: x fp32 -> bf16 -> LDS (256x64) ----
        f32x4 xv[8];
        #pragma unroll
        for (int q = 0; q < 8; ++q)
            xv[q] = *reinterpret_cast<const f32x4*>(xp + k0 + q * 4);
        #pragma unroll
        for (int q = 0; q < 4; ++q) {
            short8 v;
            #pragma unroll
            for (int j = 0; j < 4; ++j) {
                v[j]     = f2bs(xv[2 * q][j]);
                v[j + 4] = f2bs(xv[2 * q + 1][j]);
            }
            *reinterpret_cast<short8*>(&sA[swz(arow, acol + q * 8)]) = v;
        }

        // ---- stage B: W_eff = W + (Wu*lscale) @ Wd -> bf16 -> LDS (128x64) ----
        f32x4 wd[RANK];
        #pragma unroll
        for (int r = 0; r < RANK; ++r)
            wd[r] = *reinterpret_cast<const f32x4*>(wdp + (long)r * D_IN + k0);
        #pragma unroll
        for (int s = 0; s < 4; ++s) {
            const int n = nr + 32 * s;
            f32x4 wv = *reinterpret_cast<const f32x4*>(wp + (long)n * D_IN + k0);
            short4v e;
            #pragma unroll
            for (int j = 0; j < 4; ++j) {
                float v = wv[j] + u[s][0] * wd[0][j] + u[s][1] * wd[1][j]
                                + u[s][2] * wd[2][j] + u[s][3] * wd[3][j];
                e[j] = f2bs(v);
            }
            *reinterpret_cast<short4v*>(&sB[swz(n, kg * 4)]) = e;
        }

        __syncthreads();

        // ---- MFMA inner loop: 2 k-steps of 32, 16 MFMAs each ----
        #pragma unroll
        for (int ks = 0; ks < 2; ++ks) {
            short8 af[4], bfr[4];
            #pragma unroll
            for (int mi = 0; mi < 4; ++mi)
                af[mi] = *reinterpret_cast<const short8*>(
                    &sA[swz(wm + mi * 16 + lr, ks * 32 + quad * 8)]);
            #pragma unroll
            for (int ni = 0; ni < 4; ++ni)
                bfr[ni] = *reinterpret_cast<const short8*>(
                    &sB[swz(wn + ni * 16 + lr, ks * 32 + quad * 8)]);
            #pragma unroll
            for (int mi = 0; mi < 4; ++mi)
                #pragma unroll
                for (int ni = 0; ni < 4; ++ni)
                    acc[mi][ni] = __builtin_amdgcn_mfma_f32_16x16x32_bf16(
                        af[mi], bfr[ni], acc[mi][ni], 0, 0, 0);
        }
    }

    // ---- epilogue: C/D layout col=lane&15, row=quad*4+reg (m89-verified) ----
    #pragma unroll
    for (int mi = 0; mi < 4; ++mi) {
        #pragma unroll
        for (int ni = 0; ni < 4; ++ni) {
            float* op = out + (long)(gm + wm + mi * 16 + quad * 4) * D_OUT
                            + gn + wn + ni * 16 + lr;
            #pragma unroll
            for (int j = 0; j < 4; ++j) op[(long)j * D_OUT] = acc[mi][ni][j];
        }
    }
}

// ---------------------------------------------------------------------------
// Fallback for non-dividing shapes: the round-0 verified kernel (BM=128).
// ---------------------------------------------------------------------------
__global__ __launch_bounds__(256, 2)
void lora_fused_gemm_fb(const float* __restrict__ x,
                        const int* __restrict__ lora_id,
                        const float* __restrict__ W,
                        const float* __restrict__ Wd,
                        const float* __restrict__ Wu,
                        float* __restrict__ out,
                        int t_len, int ntiles_n) {
    const int BM = 128;
    __shared__ short sA[128 * BK];
    __shared__ short sB[BN * BK];

    const int tid = threadIdx.x;
    const int bx = blockIdx.x;
    const int ntile = bx % ntiles_n;
    const int mtile = bx / ntiles_n;
    const int gm = mtile * BM;
    const int gn = ntile * BN;

    const int chunk = gm / t_len;
    const int lid_raw = lora_id[chunk];
    const bool active = lid_raw >= 0;
    const int idx = active ? (lid_raw / LORA_STRIDE) : 0;
    const float lscale = active ? 1.0f : 0.0f;

    const int arow = tid >> 1;
    const int acol = (tid & 1) * 32;
    const float* xp = x + (long)(gm + arow) * D_IN + acol;

    const int kg = tid & 15;
    const int nr = tid >> 4;
    const float* wp = W + (long)gn * D_IN + kg * 4;
    const float* wdp = Wd + (long)idx * RANK * D_IN + kg * 4;

    f32x4 u[8];
    #pragma unroll
    for (int s = 0; s < 8; ++s) {
        f32x4 t = *reinterpret_cast<const f32x4*>(
            Wu + ((long)idx * D_OUT + gn + nr + 16 * s) * RANK);
        #pragma unroll
        for (int j = 0; j < 4; ++j) u[s][j] = t[j] * lscale;
    }

    const int wave = tid >> 6;
    const int lane = tid & 63;
    const int wm = (wave & 1) * 64;
    const int wn = (wave >> 1) * 64;
    const int quad = lane >> 4;
    const int lr = lane & 15;

    f32x4 acc[4][4];
    #pragma unroll
    for (int a = 0; a < 4; ++a)
        #pragma unroll
        for (int b = 0; b < 4; ++b)
            #pragma unroll
            for (int j = 0; j < 4; ++j) acc[a][b][j] = 0.f;

    for (int k0 = 0; k0 < D_IN; k0 += BK) {
        if (k0) __syncthreads();

        f32x4 xv[8];
        #pragma unroll
        for (int q = 0; q < 8; ++q)
            xv[q] = *reinterpret_cast<const f32x4*>(xp + k0 + q * 4);
        #pragma unroll
        for (int q = 0; q < 4; ++q) {
            short8 v;
            #pragma unroll
            for (int j = 0; j < 4; ++j) {
                v[j]     = f2bs(xv[2 * q][j]);
                v[j + 4] = f2bs(xv[2 * q + 1][j]);
            }
            *reinterpret_cast<short8*>(&sA[swz(arow, acol + q * 8)]) = v;
        }

        f32x4 wd[RANK];
        #pragma unroll
        for (int r = 0; r < RANK; ++r)
            wd[r] = *reinterpret_cast<const f32x4*>(wdp + (long)r * D_IN + k0);
        #pragma unroll
        for (int s = 0; s < 8; ++s) {
            const int n = nr + 16 * s;
            f32x4 wv = *reinterpret_cast<const f32x4*>(wp + (long)n * D_IN + k0);
            short4v e;
            #pragma unroll
            for (int j = 0; j < 4; ++j) {
                float v = wv[j] + u[s][0] * wd[0][j] + u[s][1] * wd[1][j]
                                + u[s][2] * wd[2][j] + u[s][3] * wd[3][j];
                e[j] = f2bs(v);
            }
            *reinterpret_cast<short4v*>(&sB[swz(n, kg * 4)]) = e;
        }

        __syncthreads();

        #pragma unroll
        for (int ks = 0; ks < 2; ++ks) {
            short8 af[4], bfr[4];
            #pragma unroll
            for (int mi = 0; mi < 4; ++mi)
                af[mi] = *reinterpret_cast<const short8*>(
                    &sA[swz(wm + mi * 16 + lr, ks * 32 + quad * 8)]);
            #pragma unroll
            for (int ni = 0; ni < 4; ++ni)
                bfr[ni] = *reinterpret_cast<const short8*>(
                    &sB[swz(wn + ni * 16 + lr, ks * 32 + quad * 8)]);
            #pragma unroll
            for (int mi = 0; mi < 4; ++mi)
                #pragma unroll
                for (int ni = 0; ni < 4; ++ni)
                    acc[mi][ni] = __builtin_amdgcn_mfma_f32_16x16x32_bf16(
                        af[mi], bfr[ni], acc[mi][ni], 0, 0, 0);
        }
    }

    #pragma unroll
    for (int mi = 0; mi < 4; ++mi) {
        #pragma unroll
        for (int ni = 0; ni < 4; ++ni) {
            float* op = out + (long)(gm + wm + mi * 16 + quad * 4) * D_OUT
                            + gn + wn + ni * 16 + lr;
            #pragma unroll
            for (int j = 0; j < 4; ++j) op[(long)j * D_OUT] = acc[mi][ni][j];
        }
    }
}

extern "C" void kernel_launch(void* const* d_in, const int* in_sizes, int n_in,
                              void* d_out, int out_size, void* d_ws, size_t ws_size,
                              hipStream_t stream) {
    const float* x   = (const float*)d_in[0];
    const int* lid   = (const int*)d_in[1];
    const float* W   = (const float*)d_in[2];
    const float* Wd  = (const float*)d_in[3];
    const float* Wu  = (const float*)d_in[4];
    float* out       = (float*)d_out;

    const int M = in_sizes[0] / D_IN;     // 65536
    const int G = in_sizes[1];            // 16
    const int t_len = M / G;              // 4096
    const int ntiles_n = D_OUT / BN;      // 10

    if (M % 256 == 0 && t_len % 256 == 0 && (((M / 256) * ntiles_n) & 7) == 0) {
        const int nblocks = (M / 256) * ntiles_n;   // 2560 (divisible by 8 XCDs)
        lora_fused_gemm_bm256<<<nblocks, 512, 0, stream>>>(
            x, lid, W, Wd, Wu, out, t_len, ntiles_n);
    } else {
        const int nblocks = (M / 128) * ntiles_n;
        lora_fused_gemm_fb<<<nblocks, 256, 0, stream>>>(
            x, lid, W, Wd, Wu, out, t_len, ntiles_n);
    }
}

// Round 4
// 1080.471 us; speedup vs baseline: 1.2821x; 1.2821x over previous
//
#include <hip/hip_runtime.h>
#include <hip/hip_bf16.h>

typedef __attribute__((ext_vector_type(8))) short short8;   // 8 bf16 (4 VGPR) MFMA A/B frag
typedef __attribute__((ext_vector_type(4))) short short4v;  // 4 bf16 (8B)
typedef __attribute__((ext_vector_type(4))) float f32x4;    // MFMA C/D frag

#define D_IN 1280
#define D_OUT 1280
#define RANK 4
#define LORA_STRIDE 4
#define BM 128
#define BN 128
#define BK 64
#define NK (D_IN / BK)   // 20

// fp32 -> bf16 round-to-nearest-even, bit-cast to short for LDS storage
__device__ __forceinline__ short f2bs(float f) {
    __hip_bfloat16 h = __float2bfloat16(f);
    return __builtin_bit_cast(short, h);
}

// LDS layout: row-major [row][64 bf16], 16-B chunk index XORed with (row&7)
// to spread banks for both staging writes and b128 frag reads. (0 measured
// bank conflicts — do not touch.)
__device__ __forceinline__ int swz(int row, int k) {
    return row * BK + ((((k >> 3) ^ row) & 7) << 3) + (k & 7);
}

// ---------------------------------------------------------------------------
// 2-phase double-buffered pipeline (T3-minimum), BM=128, 256 threads,
// 2 blocks/CU. Per K-step: barrier -> issue loads(k+1) -> MFMA from buf[cur]
// -> cvt+write buf[cur^1]. Loads are issued AFTER the barrier (so the
// compiler's vmcnt(0) drain before s_barrier never waits on them) and their
// consumers are in the SAME barrier region (so the scheduler cannot sink
// them across the barrier as it did with the failed cross-iteration
// prefetch). One barrier per K-step instead of two.
// ---------------------------------------------------------------------------
__global__ __launch_bounds__(256, 2)
void lora_fused_gemm_db(const float* __restrict__ x,      // [M][D_IN]
                        const int* __restrict__ lora_id,  // [G]
                        const float* __restrict__ W,      // [D_OUT][D_IN]
                        const float* __restrict__ Wd,     // [L][RANK][D_IN]
                        const float* __restrict__ Wu,     // [L][D_OUT][RANK]
                        float* __restrict__ out,          // [M][D_OUT]
                        int t_len, int ntiles_n) {
    __shared__ short sA[2][BM * BK];  // 32 KB
    __shared__ short sB[2][BN * BK];  // 32 KB

    const int tid = threadIdx.x;

    // T1: XCD-aware chunked remap (proven: halves FETCH by keeping an
    // m-tile's n-blocks on one XCD's L2). nwg = 5120, divisible by 8.
    const int nwg = gridDim.x;
    const int cpx = nwg >> 3;
    const int bsw = (blockIdx.x & 7) * cpx + (blockIdx.x >> 3);
    const int ntile = bsw % ntiles_n;
    const int mtile = bsw / ntiles_n;
    const int gm = mtile * BM;
    const int gn = ntile * BN;

    const int chunk = gm / t_len;       // block-uniform (BM divides t_len)
    const int lid_raw = lora_id[chunk];
    const bool active = lid_raw >= 0;
    const int idx = active ? (lid_raw / LORA_STRIDE) : 0;
    const float lscale = active ? 1.0f : 0.0f;  // SCALE = 1.0

    // A staging map: row = tid>>1, 32 contiguous k at (tid&1)*32
    const int arow = tid >> 1;
    const int acol = (tid & 1) * 32;
    const float* xp = x + (long)(gm + arow) * D_IN + acol;

    // B staging map: k-group kg of 4, rows nr+16s, s=0..7
    const int kg = tid & 15;
    const int nr = tid >> 4;
    const float* wp = W + (long)gn * D_IN + kg * 4;
    const float* wdp = Wd + (long)idx * RANK * D_IN + kg * 4;

    // Wu columns for this thread's 8 n-rows: fixed over the K-loop; pre-scaled
    f32x4 u[8];
    #pragma unroll
    for (int s = 0; s < 8; ++s) {
        f32x4 t = *reinterpret_cast<const f32x4*>(
            Wu + ((long)idx * D_OUT + gn + nr + 16 * s) * RANK);
        #pragma unroll
        for (int j = 0; j < 4; ++j) u[s][j] = t[j] * lscale;
    }

    // MFMA wave layout: 2x2 waves, each 64x64 = 4x4 tiles of 16x16
    const int wave = tid >> 6;
    const int lane = tid & 63;
    const int wm = (wave & 1) * 64;
    const int wn = (wave >> 1) * 64;
    const int quad = lane >> 4;
    const int lr = lane & 15;

    f32x4 acc[4][4];
    #pragma unroll
    for (int a = 0; a < 4; ++a)
        #pragma unroll
        for (int b = 0; b < 4; ++b)
            #pragma unroll
            for (int j = 0; j < 4; ++j) acc[a][b][j] = 0.f;

    // Staging registers — live across the MFMA phase in steady state (~80 VGPR;
    // budget 256 under (256,2), so no spill expected).
    f32x4 xv[8], wd[RANK], wv[8];

    // ---- prologue: load + stage K-step 0 into buffer 0 ----
    #pragma unroll
    for (int q = 0; q < 8; ++q)
        xv[q] = *reinterpret_cast<const f32x4*>(xp + q * 4);
    #pragma unroll
    for (int r = 0; r < RANK; ++r)
        wd[r] = *reinterpret_cast<const f32x4*>(wdp + (long)r * D_IN);
    #pragma unroll
    for (int s = 0; s < 8; ++s)
        wv[s] = *reinterpret_cast<const f32x4*>(wp + (long)(nr + 16 * s) * D_IN);

    #pragma unroll
    for (int q = 0; q < 4; ++q) {
        short8 v;
        #pragma unroll
        for (int j = 0; j < 4; ++j) {
            v[j]     = f2bs(xv[2 * q][j]);
            v[j + 4] = f2bs(xv[2 * q + 1][j]);
        }
        *reinterpret_cast<short8*>(&sA[0][swz(arow, acol + q * 8)]) = v;
    }
    #pragma unroll
    for (int s = 0; s < 8; ++s) {
        const int n = nr + 16 * s;
        short4v e;
        #pragma unroll
        for (int j = 0; j < 4; ++j) {
            float v = wv[s][j] + u[s][0] * wd[0][j] + u[s][1] * wd[1][j]
                               + u[s][2] * wd[2][j] + u[s][3] * wd[3][j];
            e[j] = f2bs(v);
        }
        *reinterpret_cast<short4v*>(&sB[0][swz(n, kg * 4)]) = e;
    }

    int cur = 0;
    for (int kt = 0; kt < NK; ++kt) {
        __syncthreads();  // buf[cur] writes visible; buf[cur^1] safe to overwrite

        // ---- issue loads for K-step kt+1 (latency hides under MFMA phase) ----
        const bool more = (kt + 1) < NK;
        if (more) {
            const int kn = (kt + 1) * BK;
            #pragma unroll
            for (int q = 0; q < 8; ++q)
                xv[q] = *reinterpret_cast<const f32x4*>(xp + kn + q * 4);
            #pragma unroll
            for (int r = 0; r < RANK; ++r)
                wd[r] = *reinterpret_cast<const f32x4*>(wdp + (long)r * D_IN + kn);
            #pragma unroll
            for (int s = 0; s < 8; ++s)
                wv[s] = *reinterpret_cast<const f32x4*>(
                    wp + (long)(nr + 16 * s) * D_IN + kn);
        }

        // ---- MFMA phase: 2 k-steps of 32, 16 MFMAs each, from buf[cur] ----
        const short* cA = sA[cur];
        const short* cB = sB[cur];
        #pragma unroll
        for (int ks = 0; ks < 2; ++ks) {
            short8 af[4], bfr[4];
            #pragma unroll
            for (int mi = 0; mi < 4; ++mi)
                af[mi] = *reinterpret_cast<const short8*>(
                    &cA[swz(wm + mi * 16 + lr, ks * 32 + quad * 8)]);
            #pragma unroll
            for (int ni = 0; ni < 4; ++ni)
                bfr[ni] = *reinterpret_cast<const short8*>(
                    &cB[swz(wn + ni * 16 + lr, ks * 32 + quad * 8)]);
            #pragma unroll
            for (int mi = 0; mi < 4; ++mi)
                #pragma unroll
                for (int ni = 0; ni < 4; ++ni)
                    acc[mi][ni] = __builtin_amdgcn_mfma_f32_16x16x32_bf16(
                        af[mi], bfr[ni], acc[mi][ni], 0, 0, 0);
        }

        // ---- stage K-step kt+1 into buf[cur^1] (vmcnt waits land here) ----
        if (more) {
            short* nA = sA[cur ^ 1];
            short* nB = sB[cur ^ 1];
            #pragma unroll
            for (int q = 0; q < 4; ++q) {
                short8 v;
                #pragma unroll
                for (int j = 0; j < 4; ++j) {
                    v[j]     = f2bs(xv[2 * q][j]);
                    v[j + 4] = f2bs(xv[2 * q + 1][j]);
                }
                *reinterpret_cast<short8*>(&nA[swz(arow, acol + q * 8)]) = v;
            }
            #pragma unroll
            for (int s = 0; s < 8; ++s) {
                const int n = nr + 16 * s;
                short4v e;
                #pragma unroll
                for (int j = 0; j < 4; ++j) {
                    float v = wv[s][j] + u[s][0] * wd[0][j] + u[s][1] * wd[1][j]
                                       + u[s][2] * wd[2][j] + u[s][3] * wd[3][j];
                    e[j] = f2bs(v);
                }
                *reinterpret_cast<short4v*>(&nB[swz(n, kg * 4)]) = e;
            }
        }
        cur ^= 1;
    }

    // ---- epilogue: C/D layout col=lane&15, row=quad*4+reg (m89-verified) ----
    #pragma unroll
    for (int mi = 0; mi < 4; ++mi) {
        #pragma unroll
        for (int ni = 0; ni < 4; ++ni) {
            float* op = out + (long)(gm + wm + mi * 16 + quad * 4) * D_OUT
                            + gn + wn + ni * 16 + lr;
            #pragma unroll
            for (int j = 0; j < 4; ++j) op[(long)j * D_OUT] = acc[mi][ni][j];
        }
    }
}

// ---------------------------------------------------------------------------
// Fallback for non-dividing shapes: the round-0 verified kernel (BM=128,
// single-buffered, no swizzle remap dependency on divisibility).
// ---------------------------------------------------------------------------
__global__ __launch_bounds__(256, 2)
void lora_fused_gemm_fb(const float* __restrict__ x,
                        const int* __restrict__ lora_id,
                        const float* __restrict__ W,
                        const float* __restrict__ Wd,
                        const float* __restrict__ Wu,
                        float* __restrict__ out,
                        int t_len, int ntiles_n) {
    __shared__ short sA[BM * BK];
    __shared__ short sB[BN * BK];

    const int tid = threadIdx.x;
    const int bx = blockIdx.x;
    const int ntile = bx % ntiles_n;
    const int mtile = bx / ntiles_n;
    const int gm = mtile * BM;
    const int gn = ntile * BN;

    const int chunk = gm / t_len;
    const int lid_raw = lora_id[chunk];
    const bool active = lid_raw >= 0;
    const int idx = active ? (lid_raw / LORA_STRIDE) : 0;
    const float lscale = active ? 1.0f : 0.0f;

    const int arow = tid >> 1;
    const int acol = (tid & 1) * 32;
    const float* xp = x + (long)(gm + arow) * D_IN + acol;

    const int kg = tid & 15;
    const int nr = tid >> 4;
    const float* wp = W + (long)gn * D_IN + kg * 4;
    const float* wdp = Wd + (long)idx * RANK * D_IN + kg * 4;

    f32x4 u[8];
    #pragma unroll
    for (int s = 0; s < 8; ++s) {
        f32x4 t = *reinterpret_cast<const f32x4*>(
            Wu + ((long)idx * D_OUT + gn + nr + 16 * s) * RANK);
        #pragma unroll
        for (int j = 0; j < 4; ++j) u[s][j] = t[j] * lscale;
    }

    const int wave = tid >> 6;
    const int lane = tid & 63;
    const int wm = (wave & 1) * 64;
    const int wn = (wave >> 1) * 64;
    const int quad = lane >> 4;
    const int lr = lane & 15;

    f32x4 acc[4][4];
    #pragma unroll
    for (int a = 0; a < 4; ++a)
        #pragma unroll
        for (int b = 0; b < 4; ++b)
            #pragma unroll
            for (int j = 0; j < 4; ++j) acc[a][b][j] = 0.f;

    for (int k0 = 0; k0 < D_IN; k0 += BK) {
        if (k0) __syncthreads();

        f32x4 xv[8];
        #pragma unroll
        for (int q = 0; q < 8; ++q)
            xv[q] = *reinterpret_cast<const f32x4*>(xp + k0 + q * 4);
        #pragma unroll
        for (int q = 0; q < 4; ++q) {
            short8 v;
            #pragma unroll
            for (int j = 0; j < 4; ++j) {
                v[j]     = f2bs(xv[2 * q][j]);
                v[j + 4] = f2bs(xv[2 * q + 1][j]);
            }
            *reinterpret_cast<short8*>(&sA[swz(arow, acol + q * 8)]) = v;
        }

        f32x4 wd[RANK];
        #pragma unroll
        for (int r = 0; r < RANK; ++r)
            wd[r] = *reinterpret_cast<const f32x4*>(wdp + (long)r * D_IN + k0);
        #pragma unroll
        for (int s = 0; s < 8; ++s) {
            const int n = nr + 16 * s;
            f32x4 wv = *reinterpret_cast<const f32x4*>(wp + (long)n * D_IN + k0);
            short4v e;
            #pragma unroll
            for (int j = 0; j < 4; ++j) {
                float v = wv[j] + u[s][0] * wd[0][j] + u[s][1] * wd[1][j]
                                + u[s][2] * wd[2][j] + u[s][3] * wd[3][j];
                e[j] = f2bs(v);
            }
            *reinterpret_cast<short4v*>(&sB[swz(n, kg * 4)]) = e;
        }

        __syncthreads();

        #pragma unroll
        for (int ks = 0; ks < 2; ++ks) {
            short8 af[4], bfr[4];
            #pragma unroll
            for (int mi = 0; mi < 4; ++mi)
                af[mi] = *reinterpret_cast<const short8*>(
                    &sA[swz(wm + mi * 16 + lr, ks * 32 + quad * 8)]);
            #pragma unroll
            for (int ni = 0; ni < 4; ++ni)
                bfr[ni] = *reinterpret_cast<const short8*>(
                    &sB[swz(wn + ni * 16 + lr, ks * 32 + quad * 8)]);
            #pragma unroll
            for (int mi = 0; mi < 4; ++mi)
                #pragma unroll
                for (int ni = 0; ni < 4; ++ni)
                    acc[mi][ni] = __builtin_amdgcn_mfma_f32_16x16x32_bf16(
                        af[mi], bfr[ni], acc[mi][ni], 0, 0, 0);
        }
    }

    #pragma unroll
    for (int mi = 0; mi < 4; ++mi) {
        #pragma unroll
        for (int ni = 0; ni < 4; ++ni) {
            float* op = out + (long)(gm + wm + mi * 16 + quad * 4) * D_OUT
                            + gn + wn + ni * 16 + lr;
            #pragma unroll
            for (int j = 0; j < 4; ++j) op[(long)j * D_OUT] = acc[mi][ni][j];
        }
    }
}

extern "C" void kernel_launch(void* const* d_in, const int* in_sizes, int n_in,
                              void* d_out, int out_size, void* d_ws, size_t ws_size,
                              hipStream_t stream) {
    const float* x   = (const float*)d_in[0];
    const int* lid   = (const int*)d_in[1];
    const float* W   = (const float*)d_in[2];
    const float* Wd  = (const float*)d_in[3];
    const float* Wu  = (const float*)d_in[4];
    float* out       = (float*)d_out;

    const int M = in_sizes[0] / D_IN;     // 65536
    const int G = in_sizes[1];            // 16
    const int t_len = M / G;              // 4096
    const int ntiles_n = D_OUT / BN;      // 10
    const int nblocks = (M / BM) * ntiles_n;  // 5120

    if (M % BM == 0 && t_len % BM == 0 && (nblocks & 7) == 0) {
        lora_fused_gemm_db<<<nblocks, 256, 0, stream>>>(
            x, lid, W, Wd, Wu, out, t_len, ntiles_n);
    } else {
        lora_fused_gemm_fb<<<nblocks, 256, 0, stream>>>(
            x, lid, W, Wd, Wu, out, t_len, ntiles_n);
    }
}